// Round 20
// baseline (155.327 us; speedup 1.0000x reference)
//
#include <hip/hip_runtime.h>
#include <hip/hip_bf16.h>

typedef _Float16 half8 __attribute__((ext_vector_type(8)));
typedef _Float16 half4v __attribute__((ext_vector_type(4)));
typedef _Float16 half2 __attribute__((ext_vector_type(2)));
typedef float f32x4 __attribute__((ext_vector_type(4)));

constexpr int NT = 4096;   // tokens
constexpr int CH = 1024;   // channels
constexpr int NH = 16;     // heads
constexpr int HD = 64;     // head dim
constexpr int C3 = 3072;   // 3*CH

#if __has_builtin(__builtin_amdgcn_exp2f)
#define EXP2(x) __builtin_amdgcn_exp2f(x)
#else
#define EXP2(x) exp2f(x)
#endif

#define GLOAD_LDS16(gp, lp) __builtin_amdgcn_global_load_lds( \
    (const __attribute__((address_space(1))) void*)(gp),      \
    (__attribute__((address_space(3))) void*)(lp), 16, 0, 0)

// counted waits (T4): loads stay in flight across raw barriers
#define WAITCNT3 do { asm volatile("s_waitcnt vmcnt(3)" ::: "memory"); \
                      __builtin_amdgcn_sched_barrier(0); } while (0)
#define WAITCNT4 do { asm volatile("s_waitcnt vmcnt(4)" ::: "memory"); \
                      __builtin_amdgcn_sched_barrier(0); } while (0)
#define WAITCNT0 do { asm volatile("s_waitcnt vmcnt(0)" ::: "memory"); \
                      __builtin_amdgcn_sched_barrier(0); } while (0)

static __device__ inline half2 pk_f16(float a, float b) {
  auto r = __builtin_amdgcn_cvt_pkrtz(a, b);   // v_cvt_pkrtz_f16_f32
  return *(half2*)&r;
}

// ---------------- fused f32 -> f16 convert (x, w_qkv, w_out in one launch) ----------------
__global__ __launch_bounds__(256) void cvt3_kernel(const float* __restrict__ a, int na4,
                                                   const float* __restrict__ b, int nb4,
                                                   const float* __restrict__ c, int nc4,
                                                   _Float16* __restrict__ oa,
                                                   _Float16* __restrict__ ob,
                                                   _Float16* __restrict__ oc) {
  int i = blockIdx.x * 256 + threadIdx.x;
  const float* src; _Float16* dst; int j = i;
  if (i < na4) { src = a; dst = oa; }
  else if (i < na4 + nb4) { src = b; dst = ob; j = i - na4; }
  else if (i < na4 + nb4 + nc4) { src = c; dst = oc; j = i - na4 - nb4; }
  else return;
  float4 v = ((const float4*)src)[j];
  half4v h;
  h[0] = (_Float16)v.x; h[1] = (_Float16)v.y; h[2] = (_Float16)v.z; h[3] = (_Float16)v.w;
  ((half4v*)dst)[j] = h;
}

// ---------------- RoPE cos/sin table: csn[n*32 + j] = {cos, sin}(ang(n,j)) ----------------
__global__ __launch_bounds__(256) void rope_tab_kernel(const int* __restrict__ coords,
                                                       float2* __restrict__ csn) {
  int idx = blockIdx.x * 256 + threadIdx.x;   // NT*32 exact
  int n = idx >> 5, j = idx & 31;
  float ang = (float)coords[n * 5 + 1 + (j >> 3)] * __expf(-(float)(j & 7) * 0.14391157f);
  csn[idx] = make_float2(cosf(ang), sinf(ang));
}

// ---------------- fused QKV GEMM (128x256) + RMSNorm + RoPE + K/V frag-swizzle ----------------
// (r19 structure, unchanged this round)
__global__ __launch_bounds__(512, 4) void gemm_qkv(const _Float16* __restrict__ A,
                                                   const _Float16* __restrict__ Bt,
                                                   const float2* __restrict__ csn,
                                                   const float* __restrict__ gq,
                                                   const float* __restrict__ gk,
                                                   _Float16* __restrict__ Qh,
                                                   _Float16* __restrict__ KF,
                                                   _Float16* __restrict__ VF) {
  __shared__ __align__(16) char smem[73728];          // staging 48KB; epilogue 8x9216
  auto As = (_Float16(*)[128][32])smem;               // [2][128][32] = 16KB
  auto Bs = (_Float16(*)[256][32])(smem + 16384);     // [2][256][32] = 32KB
  const int K = CH;
  const int tid = threadIdx.x;
  const int lane = tid & 63, w = tid >> 6;
  const int l15 = lane & 15, l4 = lane >> 4;
  int nwg = gridDim.x, cpx = nwg >> 3;
  int wg = (blockIdx.x & 7) * cpx + (blockIdx.x >> 3);   // bijective XCD swizzle
  const int nbx = NT / 128;                           // 32
  const int bm = wg % nbx, bn = wg / nbx;
  const int m0 = bm * 128, n0 = bn * 256;
  const int wr = w >> 2, wc = w & 3;                  // 2 x 4 waves
  const int arow = w * 16 + (lane >> 2);              // A staging: 4 lanes/row
  const int acol = (lane & 3) * 8;
  const int rb = w * 32;                              // B staging band
  const int rl = lane >> 2;
  const int cb = (lane & 3) * 8;
  f32x4 acc[4][4] = {};
  auto stage = [&](int k0, int buf) {   // exactly 3 gload_lds per thread
    GLOAD_LDS16(A  + (size_t)(m0 + arow) * K + k0 + acol,       &As[buf][w * 16][0]);
    GLOAD_LDS16(Bt + (size_t)(n0 + rb + rl) * K + k0 + cb,      &Bs[buf][rb][0]);
    GLOAD_LDS16(Bt + (size_t)(n0 + rb + 16 + rl) * K + k0 + cb, &Bs[buf][rb + 16][0]);
  };
  auto compute = [&](int buf) {
    half8 af[4], bf[4];
#pragma unroll
    for (int mt = 0; mt < 4; ++mt) af[mt] = *(half8*)&As[buf][wr * 64 + mt * 16 + l15][l4 * 8];
#pragma unroll
    for (int nt = 0; nt < 4; ++nt) bf[nt] = *(half8*)&Bs[buf][wc * 64 + nt * 16 + l15][l4 * 8];
    __builtin_amdgcn_s_setprio(1);
#pragma unroll
    for (int mt = 0; mt < 4; ++mt)
#pragma unroll
      for (int nt = 0; nt < 4; ++nt)
        acc[mt][nt] = __builtin_amdgcn_mfma_f32_16x16x32_f16(af[mt], bf[nt], acc[mt][nt], 0, 0, 0);
    __builtin_amdgcn_s_setprio(0);
  };
  stage(0, 0);
  stage(32, 1);
  for (int k0 = 0; k0 < K - 32; k0 += 32) {
    int buf = (k0 >> 5) & 1;
    WAITCNT3;                          // own stage(k0) done; stage(k0+32) in flight
    __builtin_amdgcn_s_barrier();      // all waves' stage(k0) done; prior buf readers done
    compute(buf);
    __builtin_amdgcn_s_barrier();      // all reads of buf done -> safe to re-stage
    if (k0 + 64 < K) stage(k0 + 64, buf);
  }
  WAITCNT0;                            // last tile: drain
  __builtin_amdgcn_s_barrier();
  compute(((K - 32) >> 5) & 1);
  __builtin_amdgcn_s_barrier();        // seal LDS reads before epilogue reuses smem
  // ---- fused epilogue (per-wave private LDS region; r16-proven formulas) ----
  const int gc0 = n0 + wc * 64;
  const int sec = gc0 >> 10;                 // 0=q, 1=k, 2=v
  const int h   = (gc0 & 1023) >> 6;
  const int K0  = m0 + wr * 64;              // token base of this wave's 64 rows
  _Float16* Lw = (_Float16*)(smem + w * 9216);   // [64][72] f16
  if (sec < 2) {                             // ---- Q/K: RMSNorm + RoPE ----
    const float* gm = (sec == 0) ? gq : gk;
    float gmm[4];
#pragma unroll
    for (int nt = 0; nt < 4; ++nt) gmm[nt] = gm[h * 64 + nt * 16 + l15];
    const float qsc = (sec == 0) ? 0.18033688f : 1.0f;   // 0.125*log2(e) for Q
#pragma unroll
    for (int mt = 0; mt < 4; ++mt)
#pragma unroll
      for (int r = 0; r < 4; ++r) {
        float ss = 0.f;
#pragma unroll
        for (int nt = 0; nt < 4; ++nt) ss += acc[mt][nt][r] * acc[mt][nt][r];
        ss += __shfl_xor(ss, 1); ss += __shfl_xor(ss, 2);
        ss += __shfl_xor(ss, 4); ss += __shfl_xor(ss, 8);
        float sc = 8.0f / fmaxf(sqrtf(ss), 1e-12f);
        int row = mt * 16 + l4 * 4 + r;      // local token row
        int n = K0 + row;
#pragma unroll
        for (int nt = 0; nt < 4; ++nt) {
          float v = acc[mt][nt][r] * sc * gmm[nt];
          float2 cz = csn[n * 32 + nt * 8 + (l15 >> 1)];
          float p = __shfl_xor(v, 1);
          float o = ((l15 & 1) == 0) ? (v * cz.x - p * cz.y) : (p * cz.y + v * cz.x);
          Lw[row * 72 + nt * 16 + l15] = (_Float16)(o * qsc);
        }
      }
  } else {                                   // ---- V: passthrough ----
#pragma unroll
    for (int mt = 0; mt < 4; ++mt)
#pragma unroll
      for (int r = 0; r < 4; ++r) {
        int row = mt * 16 + l4 * 4 + r;
#pragma unroll
        for (int nt = 0; nt < 4; ++nt)
          Lw[row * 72 + nt * 16 + l15] = (_Float16)acc[mt][nt][r];
      }
  }
  // within-wave LDS write->read: lockstep program order, no barrier needed
  const int kb = K0 >> 6;
  if (sec == 0) {                            // Q row-major: [h][NT][64]
#pragma unroll
    for (int i = 0; i < 8; ++i) {
      int row = i * 8 + (lane >> 3), col = (lane & 7) * 8;
      half8 vv = *(half8*)&Lw[row * 72 + col];
      *(half8*)(Qh + ((size_t)h * NT + K0 + row) * 64 + col) = vv;
    }
  } else if (sec == 1) {                     // K fragment-swizzled
    _Float16* base = KF + (size_t)h * NT * HD + (size_t)kb * 4096;
#pragma unroll
    for (int i = 0; i < 8; ++i) {
      int t = i >> 1, kk = i & 1;
      int i15 = lane & 15, ll4 = lane >> 4;
      // invert: t=2*(m>>5)+((m>>2)&1); i15=4*((m>>3)&3)+(m&3)
      int m = ((t >> 1) << 5) | ((i15 >> 2) << 3) | ((t & 1) << 2) | (i15 & 3);
      half8 vv = *(half8*)&Lw[m * 72 + kk * 32 + ll4 * 8];
      *(half8*)(base + (size_t)(((t * 2 + kk) * 64 + ll4 * 16 + i15) * 8)) = vv;
    }
  } else {                                   // V fragment-swizzled
    _Float16* base = VF + (size_t)h * NT * HD + (size_t)kb * 4096;
#pragma unroll
    for (int i = 0; i < 8; ++i) {
      int t = i >> 1, kk = i & 1;
      int l15v = lane & 15, l4v = lane >> 4;
      half8 vv;
#pragma unroll
      for (int jj = 0; jj < 8; ++jj)
        vv[jj] = Lw[(kk * 32 + l4v * 8 + jj) * 72 + t * 16 + l15v];
      *(half8*)(base + (size_t)(((t * 2 + kk) * 64 + l4v * 16 + l15v) * 8)) = vv;
    }
  }
}

// ---------------- GEMM (gemm2): C[M][Nn] = A[M][K] * Bt[Nn][K]^T ----------------
// (r18 structure, unchanged)
template <typename OutT>
__global__ __launch_bounds__(256) void gemm_bt(const _Float16* __restrict__ A,
                                               const _Float16* __restrict__ Bt,
                                               OutT* __restrict__ Cc,
                                               int M, int Nn, int K, int nbx) {
  __shared__ _Float16 As[2][128][32];
  __shared__ _Float16 Bs[2][128][32];
  const int tid = threadIdx.x;
  const int lane = tid & 63, w = tid >> 6;
  const int l15 = lane & 15, l4 = lane >> 4;
  int nwg = gridDim.x, cpx = nwg >> 3;
  int wg = (blockIdx.x & 7) * cpx + (blockIdx.x >> 3);
  const int m0 = (wg % nbx) * 128, n0 = (wg / nbx) * 128;
  const int wr = w >> 1, wc = w & 1;
  const int rb = w * 32;
  const int rl = lane >> 2;
  const int cb = (lane & 3) * 8;
  f32x4 acc[4][4] = {};
  auto stage = [&](int k0, int buf) {   // exactly 4 gload_lds per thread
    GLOAD_LDS16(A  + (size_t)(m0 + rb + rl) * K + k0 + cb,      &As[buf][rb][0]);
    GLOAD_LDS16(A  + (size_t)(m0 + rb + 16 + rl) * K + k0 + cb, &As[buf][rb + 16][0]);
    GLOAD_LDS16(Bt + (size_t)(n0 + rb + rl) * K + k0 + cb,      &Bs[buf][rb][0]);
    GLOAD_LDS16(Bt + (size_t)(n0 + rb + 16 + rl) * K + k0 + cb, &Bs[buf][rb + 16][0]);
  };
  auto compute = [&](int buf) {
    half8 af[4], bf[4];
#pragma unroll
    for (int mt = 0; mt < 4; ++mt) af[mt] = *(half8*)&As[buf][wr * 64 + mt * 16 + l15][l4 * 8];
#pragma unroll
    for (int nt = 0; nt < 4; ++nt) bf[nt] = *(half8*)&Bs[buf][wc * 64 + nt * 16 + l15][l4 * 8];
    __builtin_amdgcn_s_setprio(1);
#pragma unroll
    for (int mt = 0; mt < 4; ++mt)
#pragma unroll
      for (int nt = 0; nt < 4; ++nt)
        acc[mt][nt] = __builtin_amdgcn_mfma_f32_16x16x32_f16(af[mt], bf[nt], acc[mt][nt], 0, 0, 0);
    __builtin_amdgcn_s_setprio(0);
  };
  stage(0, 0);
  stage(32, 1);
  for (int k0 = 0; k0 < K - 32; k0 += 32) {
    int buf = (k0 >> 5) & 1;
    WAITCNT4;
    __builtin_amdgcn_s_barrier();
    compute(buf);
    __builtin_amdgcn_s_barrier();
    if (k0 + 64 < K) stage(k0 + 64, buf);
  }
  WAITCNT0;
  __builtin_amdgcn_s_barrier();
  compute(((K - 32) >> 5) & 1);
#pragma unroll
  for (int mt = 0; mt < 4; ++mt)
#pragma unroll
    for (int nt = 0; nt < 4; ++nt)
#pragma unroll
      for (int r = 0; r < 4; ++r) {
        int row = m0 + wr * 64 + mt * 16 + l4 * 4 + r;
        int col = n0 + wc * 64 + nt * 16 + l15;
        Cc[(size_t)row * Nn + col] = (OutT)acc[mt][nt][r];
      }
}

// ---------------- flash attention: KVBLK=128, lsum on VALU ----------------
// one block = (head, 128-row Q tile); 4 waves, 32 q-rows each; grid 512.
// Changes vs r13-champion: (1) stage 2x64-key sub-tiles per barrier pair
// (halves barrier/drain events, doubles inter-barrier ILP; 32KB LDS, still
// 2 blocks/CU); (2) lsum computed with VALU adds on the f32 e[] values
// (MFMA/tile 20 -> 16; the 4 ones-frag MFMAs were 20% of the busiest pipe),
// final reduce = 2 shfl_xor + shfl redistribute (r5-proven epilogue).
__global__ __launch_bounds__(256, 2) void attn_kernel(const _Float16* __restrict__ Qh,
                                                      const _Float16* __restrict__ KF,
                                                      const _Float16* __restrict__ VF,
                                                      _Float16* __restrict__ Oh) {
  __shared__ _Float16 KB[2][4096];
  __shared__ _Float16 VB[2][4096];
  const int tid = threadIdx.x, lane = tid & 63, w = tid >> 6;
  const int l15 = lane & 15, l4 = lane >> 4;
  int bid = blockIdx.x;
  int s = bid >> 3;
  int h = (bid & 7) * 2 + (s >> 5);
  int n0 = (s & 31) * 128;
  half8 qf[2][2];
#pragma unroll
  for (int qb = 0; qb < 2; ++qb)
#pragma unroll
    for (int kk = 0; kk < 2; ++kk)
      qf[qb][kk] = *(const half8*)(Qh + ((size_t)h * NT + n0 + w * 32 + qb * 16 + l15) * HD + kk * 32 + l4 * 8);
  f32x4 acc[2][4] = {};
  float ls[2] = {0.f, 0.f};    // per-lane lsum partials (q = l15, 16 keys/tile)
  const _Float16* KFh = KF + (size_t)h * NT * HD + w * 512 + lane * 8;
  const _Float16* VFh = VF + (size_t)h * NT * HD + w * 512 + lane * 8;
  union U { half8 v; half2 p[4]; };
  for (int kb = 0; kb < 64; kb += 2) {
    __syncthreads();               // prior pair's reads done
    {                              // stage 2 sub-tiles (block-wide, linear dest)
      size_t g0 = (size_t)kb * 4096;
      GLOAD_LDS16(KFh + g0,        &KB[0][w * 512]);
      GLOAD_LDS16(KFh + g0 + 2048, &KB[0][2048 + w * 512]);
      GLOAD_LDS16(VFh + g0,        &VB[0][w * 512]);
      GLOAD_LDS16(VFh + g0 + 2048, &VB[0][2048 + w * 512]);
      GLOAD_LDS16(KFh + g0 + 4096, &KB[1][w * 512]);
      GLOAD_LDS16(KFh + g0 + 6144, &KB[1][2048 + w * 512]);
      GLOAD_LDS16(VFh + g0 + 4096, &VB[1][w * 512]);
      GLOAD_LDS16(VFh + g0 + 6144, &VB[1][2048 + w * 512]);
    }
    __syncthreads();               // vmcnt drain -> both sub-tiles ready
#pragma unroll
    for (int sub = 0; sub < 2; ++sub) {
      f32x4 sv[2][4] = {};
      __builtin_amdgcn_s_setprio(1);
#pragma unroll
      for (int t = 0; t < 4; ++t)
#pragma unroll
        for (int kk = 0; kk < 2; ++kk) {
          half8 kf = *(half8*)&KB[sub][(t * 2 + kk) * 512 + lane * 8];
          sv[0][t] = __builtin_amdgcn_mfma_f32_16x16x32_f16(kf, qf[0][kk], sv[0][t], 0, 0, 0);
          sv[1][t] = __builtin_amdgcn_mfma_f32_16x16x32_f16(kf, qf[1][kk], sv[1][t], 0, 0, 0);
        }
      __builtin_amdgcn_s_setprio(0);
      U u[2][2];
#pragma unroll
      for (int qb = 0; qb < 2; ++qb) {
        float e[4][4];
#pragma unroll
        for (int t = 0; t < 4; ++t)
#pragma unroll
          for (int r = 0; r < 4; ++r) e[t][r] = EXP2(sv[qb][t][r]);
        // lsum partial on VALU (tree of adds)
        float s0 = (e[0][0] + e[0][1]) + (e[0][2] + e[0][3]);
        float s1 = (e[1][0] + e[1][1]) + (e[1][2] + e[1][3]);
        float s2 = (e[2][0] + e[2][1]) + (e[2][2] + e[2][3]);
        float s3 = (e[3][0] + e[3][1]) + (e[3][2] + e[3][3]);
        ls[qb] += (s0 + s1) + (s2 + s3);
        u[qb][0].p[0] = pk_f16(e[0][0], e[0][1]); u[qb][0].p[1] = pk_f16(e[0][2], e[0][3]);
        u[qb][0].p[2] = pk_f16(e[1][0], e[1][1]); u[qb][0].p[3] = pk_f16(e[1][2], e[1][3]);
        u[qb][1].p[0] = pk_f16(e[2][0], e[2][1]); u[qb][1].p[1] = pk_f16(e[2][2], e[2][3]);
        u[qb][1].p[2] = pk_f16(e[3][0], e[3][1]); u[qb][1].p[3] = pk_f16(e[3][2], e[3][3]);
      }
      __builtin_amdgcn_s_setprio(1);
#pragma unroll
      for (int t = 0; t < 4; ++t)
#pragma unroll
        for (int kk = 0; kk < 2; ++kk) {
          half8 vf = *(half8*)&VB[sub][(t * 2 + kk) * 512 + lane * 8];
          acc[0][t] = __builtin_amdgcn_mfma_f32_16x16x32_f16(u[0][kk].v, vf, acc[0][t], 0, 0, 0);
          acc[1][t] = __builtin_amdgcn_mfma_f32_16x16x32_f16(u[1][kk].v, vf, acc[1][t], 0, 0, 0);
        }
      __builtin_amdgcn_s_setprio(0);
    }
  }
  // reduce lsum across the 4 lanes sharing l15 (xor 16, 32), then redistribute
#pragma unroll
  for (int qb = 0; qb < 2; ++qb) {
    ls[qb] += __shfl_xor(ls[qb], 16);
    ls[qb] += __shfl_xor(ls[qb], 32);
  }
#pragma unroll
  for (int qb = 0; qb < 2; ++qb) {
    float linv[4];
#pragma unroll
    for (int r = 0; r < 4; ++r) linv[r] = 1.0f / __shfl(ls[qb], l4 * 4 + r);
#pragma unroll
    for (int t = 0; t < 4; ++t)
#pragma unroll
      for (int r = 0; r < 4; ++r) {
        int row = n0 + w * 32 + qb * 16 + l4 * 4 + r;
        Oh[(size_t)row * CH + h * HD + t * 16 + l15] = (_Float16)(acc[qb][t][r] * linv[r]);
      }
  }
}

extern "C" void kernel_launch(void* const* d_in, const int* in_sizes, int n_in,
                              void* d_out, int out_size, void* d_ws, size_t ws_size,
                              hipStream_t stream) {
  const float* x      = (const float*)d_in[0];
  const int*   coords = (const int*)d_in[1];
  const float* w_qkv  = (const float*)d_in[2];
  const float* w_out  = (const float*)d_in[3];
  const float* gq     = (const float*)d_in[4];
  const float* gk     = (const float*)d_in[5];
  float* out = (float*)d_out;

  char* ws = (char*)d_ws;
  size_t off = 0;
  auto alloc = [&](size_t bytes) { char* p = ws + off; off += bytes; return p; };
  _Float16* xh   = (_Float16*)alloc((size_t)NT * CH * 2);  // x f16
  _Float16* wqh  = (_Float16*)alloc((size_t)C3 * CH * 2);  // w_qkv f16
  _Float16* woh  = (_Float16*)alloc((size_t)CH * CH * 2);  // w_out f16
  float2*   csn  = (float2*)alloc((size_t)NT * 32 * 8);    // rope cos/sin table
  _Float16* Qh   = (_Float16*)alloc((size_t)NT * CH * 2);  // [H][N][64], pre-scaled
  _Float16* KFh  = (_Float16*)alloc((size_t)NT * CH * 2);  // frag-swizzled K
  _Float16* VFh  = (_Float16*)alloc((size_t)NT * CH * 2);  // frag-swizzled V
  _Float16* Oh   = (_Float16*)alloc((size_t)NT * CH * 2);  // attn out [N][C]
  if (off > ws_size) return;  // workspace too small: fail cleanly

  int na4 = NT * CH / 4, nb4 = C3 * CH / 4, nc4 = CH * CH / 4;
  cvt3_kernel<<<(na4 + nb4 + nc4) / 256, 256, 0, stream>>>(x, na4, w_qkv, nb4, w_out, nc4,
                                                           xh, wqh, woh);
  rope_tab_kernel<<<NT * 32 / 256, 256, 0, stream>>>(coords, csn);
  gemm_qkv<<<(NT / 128) * (C3 / 256), 512, 0, stream>>>(xh, wqh, csn, gq, gk, Qh, KFh, VFh);
  attn_kernel<<<NH * (NT / 128), 256, 0, stream>>>(Qh, KFh, VFh, Oh);
  gemm_bt<float><<<(NT / 128) * (CH / 128), 256, 0, stream>>>(Oh, woh, out, NT, CH, CH, NT / 128);
}

// Round 21
// 151.179 us; speedup vs baseline: 1.0274x; 1.0274x over previous
//
#include <hip/hip_runtime.h>
#include <hip/hip_bf16.h>

typedef _Float16 half8 __attribute__((ext_vector_type(8)));
typedef _Float16 half4v __attribute__((ext_vector_type(4)));
typedef _Float16 half2 __attribute__((ext_vector_type(2)));
typedef float f32x4 __attribute__((ext_vector_type(4)));

constexpr int NT = 4096;   // tokens
constexpr int CH = 1024;   // channels
constexpr int NH = 16;     // heads
constexpr int HD = 64;     // head dim
constexpr int C3 = 3072;   // 3*CH

#if __has_builtin(__builtin_amdgcn_exp2f)
#define EXP2(x) __builtin_amdgcn_exp2f(x)
#else
#define EXP2(x) exp2f(x)
#endif

#define GLOAD_LDS16(gp, lp) __builtin_amdgcn_global_load_lds( \
    (const __attribute__((address_space(1))) void*)(gp),      \
    (__attribute__((address_space(3))) void*)(lp), 16, 0, 0)

// counted waits (T4): loads stay in flight across raw barriers
#define WAITCNT3 do { asm volatile("s_waitcnt vmcnt(3)" ::: "memory"); \
                      __builtin_amdgcn_sched_barrier(0); } while (0)
#define WAITCNT4 do { asm volatile("s_waitcnt vmcnt(4)" ::: "memory"); \
                      __builtin_amdgcn_sched_barrier(0); } while (0)
#define WAITCNT0 do { asm volatile("s_waitcnt vmcnt(0)" ::: "memory"); \
                      __builtin_amdgcn_sched_barrier(0); } while (0)

static __device__ inline half2 pk_f16(float a, float b) {
  auto r = __builtin_amdgcn_cvt_pkrtz(a, b);   // v_cvt_pkrtz_f16_f32
  return *(half2*)&r;
}

// ---------------- prep: f32->f16 converts (x, w_qkv, w_out) + RoPE table ----------------
// ranges (in units of float4 for cvt; threads for rope) appended back-to-back:
// [0,na4) x->xh ; [na4,na4+nb4) w_qkv->wqh ; [..+nc4) w_out->woh ;
// [cvt_end, cvt_end + NT*32) rope table csn.
__global__ __launch_bounds__(256) void prep_kernel(const float* __restrict__ a, int na4,
                                                   const float* __restrict__ b, int nb4,
                                                   const float* __restrict__ c, int nc4,
                                                   const int* __restrict__ coords,
                                                   _Float16* __restrict__ oa,
                                                   _Float16* __restrict__ ob,
                                                   _Float16* __restrict__ oc,
                                                   float2* __restrict__ csn) {
  int i = blockIdx.x * 256 + threadIdx.x;
  int cvt_end = na4 + nb4 + nc4;
  if (i < cvt_end) {
    const float* src; _Float16* dst; int j = i;
    if (i < na4) { src = a; dst = oa; }
    else if (i < na4 + nb4) { src = b; dst = ob; j = i - na4; }
    else { src = c; dst = oc; j = i - na4 - nb4; }
    float4 v = ((const float4*)src)[j];
    half4v h;
    h[0] = (_Float16)v.x; h[1] = (_Float16)v.y; h[2] = (_Float16)v.z; h[3] = (_Float16)v.w;
    ((half4v*)dst)[j] = h;
  } else {
    int idx = i - cvt_end;               // [0, NT*32)
    if (idx >= NT * 32) return;
    int n = idx >> 5, j = idx & 31;
    float ang = (float)coords[n * 5 + 1 + (j >> 3)] * __expf(-(float)(j & 7) * 0.14391157f);
    csn[idx] = make_float2(cosf(ang), sinf(ang));
  }
}

// ---------------- fused QKV GEMM (128x256) + RMSNorm + RoPE + K/V frag-swizzle ----------------
// (r19 structure, unchanged)
__global__ __launch_bounds__(512, 4) void gemm_qkv(const _Float16* __restrict__ A,
                                                   const _Float16* __restrict__ Bt,
                                                   const float2* __restrict__ csn,
                                                   const float* __restrict__ gq,
                                                   const float* __restrict__ gk,
                                                   _Float16* __restrict__ Qh,
                                                   _Float16* __restrict__ KF,
                                                   _Float16* __restrict__ VF) {
  __shared__ __align__(16) char smem[73728];          // staging 48KB; epilogue 8x9216
  auto As = (_Float16(*)[128][32])smem;               // [2][128][32] = 16KB
  auto Bs = (_Float16(*)[256][32])(smem + 16384);     // [2][256][32] = 32KB
  const int K = CH;
  const int tid = threadIdx.x;
  const int lane = tid & 63, w = tid >> 6;
  const int l15 = lane & 15, l4 = lane >> 4;
  int nwg = gridDim.x, cpx = nwg >> 3;
  int wg = (blockIdx.x & 7) * cpx + (blockIdx.x >> 3);   // bijective XCD swizzle
  const int nbx = NT / 128;                           // 32
  const int bm = wg % nbx, bn = wg / nbx;
  const int m0 = bm * 128, n0 = bn * 256;
  const int wr = w >> 2, wc = w & 3;                  // 2 x 4 waves
  const int arow = w * 16 + (lane >> 2);              // A staging: 4 lanes/row
  const int acol = (lane & 3) * 8;
  const int rb = w * 32;                              // B staging band
  const int rl = lane >> 2;
  const int cb = (lane & 3) * 8;
  f32x4 acc[4][4] = {};
  auto stage = [&](int k0, int buf) {   // exactly 3 gload_lds per thread
    GLOAD_LDS16(A  + (size_t)(m0 + arow) * K + k0 + acol,       &As[buf][w * 16][0]);
    GLOAD_LDS16(Bt + (size_t)(n0 + rb + rl) * K + k0 + cb,      &Bs[buf][rb][0]);
    GLOAD_LDS16(Bt + (size_t)(n0 + rb + 16 + rl) * K + k0 + cb, &Bs[buf][rb + 16][0]);
  };
  auto compute = [&](int buf) {
    half8 af[4], bf[4];
#pragma unroll
    for (int mt = 0; mt < 4; ++mt) af[mt] = *(half8*)&As[buf][wr * 64 + mt * 16 + l15][l4 * 8];
#pragma unroll
    for (int nt = 0; nt < 4; ++nt) bf[nt] = *(half8*)&Bs[buf][wc * 64 + nt * 16 + l15][l4 * 8];
    __builtin_amdgcn_s_setprio(1);
#pragma unroll
    for (int mt = 0; mt < 4; ++mt)
#pragma unroll
      for (int nt = 0; nt < 4; ++nt)
        acc[mt][nt] = __builtin_amdgcn_mfma_f32_16x16x32_f16(af[mt], bf[nt], acc[mt][nt], 0, 0, 0);
    __builtin_amdgcn_s_setprio(0);
  };
  stage(0, 0);
  stage(32, 1);
  for (int k0 = 0; k0 < K - 32; k0 += 32) {
    int buf = (k0 >> 5) & 1;
    WAITCNT3;                          // own stage(k0) done; stage(k0+32) in flight
    __builtin_amdgcn_s_barrier();      // all waves' stage(k0) done; prior buf readers done
    compute(buf);
    __builtin_amdgcn_s_barrier();      // all reads of buf done -> safe to re-stage
    if (k0 + 64 < K) stage(k0 + 64, buf);
  }
  WAITCNT0;                            // last tile: drain
  __builtin_amdgcn_s_barrier();
  compute(((K - 32) >> 5) & 1);
  __builtin_amdgcn_s_barrier();        // seal LDS reads before epilogue reuses smem
  // ---- fused epilogue (per-wave private LDS region; r16-proven formulas) ----
  const int gc0 = n0 + wc * 64;
  const int sec = gc0 >> 10;                 // 0=q, 1=k, 2=v
  const int h   = (gc0 & 1023) >> 6;
  const int K0  = m0 + wr * 64;              // token base of this wave's 64 rows
  _Float16* Lw = (_Float16*)(smem + w * 9216);   // [64][72] f16
  if (sec < 2) {                             // ---- Q/K: RMSNorm + RoPE ----
    const float* gm = (sec == 0) ? gq : gk;
    float gmm[4];
#pragma unroll
    for (int nt = 0; nt < 4; ++nt) gmm[nt] = gm[h * 64 + nt * 16 + l15];
    const float qsc = (sec == 0) ? 0.18033688f : 1.0f;   // 0.125*log2(e) for Q
#pragma unroll
    for (int mt = 0; mt < 4; ++mt)
#pragma unroll
      for (int r = 0; r < 4; ++r) {
        float ss = 0.f;
#pragma unroll
        for (int nt = 0; nt < 4; ++nt) ss += acc[mt][nt][r] * acc[mt][nt][r];
        ss += __shfl_xor(ss, 1); ss += __shfl_xor(ss, 2);
        ss += __shfl_xor(ss, 4); ss += __shfl_xor(ss, 8);
        float sc = 8.0f / fmaxf(sqrtf(ss), 1e-12f);
        int row = mt * 16 + l4 * 4 + r;      // local token row
        int n = K0 + row;
#pragma unroll
        for (int nt = 0; nt < 4; ++nt) {
          float v = acc[mt][nt][r] * sc * gmm[nt];
          float2 cz = csn[n * 32 + nt * 8 + (l15 >> 1)];
          float p = __shfl_xor(v, 1);
          float o = ((l15 & 1) == 0) ? (v * cz.x - p * cz.y) : (p * cz.y + v * cz.x);
          Lw[row * 72 + nt * 16 + l15] = (_Float16)(o * qsc);
        }
      }
  } else {                                   // ---- V: passthrough ----
#pragma unroll
    for (int mt = 0; mt < 4; ++mt)
#pragma unroll
      for (int r = 0; r < 4; ++r) {
        int row = mt * 16 + l4 * 4 + r;
#pragma unroll
        for (int nt = 0; nt < 4; ++nt)
          Lw[row * 72 + nt * 16 + l15] = (_Float16)acc[mt][nt][r];
      }
  }
  // within-wave LDS write->read: lockstep program order, no barrier needed
  const int kb = K0 >> 6;
  if (sec == 0) {                            // Q row-major: [h][NT][64]
#pragma unroll
    for (int i = 0; i < 8; ++i) {
      int row = i * 8 + (lane >> 3), col = (lane & 7) * 8;
      half8 vv = *(half8*)&Lw[row * 72 + col];
      *(half8*)(Qh + ((size_t)h * NT + K0 + row) * 64 + col) = vv;
    }
  } else if (sec == 1) {                     // K fragment-swizzled
    _Float16* base = KF + (size_t)h * NT * HD + (size_t)kb * 4096;
#pragma unroll
    for (int i = 0; i < 8; ++i) {
      int t = i >> 1, kk = i & 1;
      int i15 = lane & 15, ll4 = lane >> 4;
      // invert: t=2*(m>>5)+((m>>2)&1); i15=4*((m>>3)&3)+(m&3)
      int m = ((t >> 1) << 5) | ((i15 >> 2) << 3) | ((t & 1) << 2) | (i15 & 3);
      half8 vv = *(half8*)&Lw[m * 72 + kk * 32 + ll4 * 8];
      *(half8*)(base + (size_t)(((t * 2 + kk) * 64 + ll4 * 16 + i15) * 8)) = vv;
    }
  } else {                                   // V fragment-swizzled
    _Float16* base = VF + (size_t)h * NT * HD + (size_t)kb * 4096;
#pragma unroll
    for (int i = 0; i < 8; ++i) {
      int t = i >> 1, kk = i & 1;
      int l15v = lane & 15, l4v = lane >> 4;
      half8 vv;
#pragma unroll
      for (int jj = 0; jj < 8; ++jj)
        vv[jj] = Lw[(kk * 32 + l4v * 8 + jj) * 72 + t * 16 + l15v];
      *(half8*)(base + (size_t)(((t * 2 + kk) * 64 + l4v * 16 + l15v) * 8)) = vv;
    }
  }
}

// ---------------- GEMM (gemm2): C[M][Nn] = A[M][K] * Bt[Nn][K]^T ----------------
// (r18 structure, unchanged)
template <typename OutT>
__global__ __launch_bounds__(256) void gemm_bt(const _Float16* __restrict__ A,
                                               const _Float16* __restrict__ Bt,
                                               OutT* __restrict__ Cc,
                                               int M, int Nn, int K, int nbx) {
  __shared__ _Float16 As[2][128][32];
  __shared__ _Float16 Bs[2][128][32];
  const int tid = threadIdx.x;
  const int lane = tid & 63, w = tid >> 6;
  const int l15 = lane & 15, l4 = lane >> 4;
  int nwg = gridDim.x, cpx = nwg >> 3;
  int wg = (blockIdx.x & 7) * cpx + (blockIdx.x >> 3);
  const int m0 = (wg % nbx) * 128, n0 = (wg / nbx) * 128;
  const int wr = w >> 1, wc = w & 1;
  const int rb = w * 32;
  const int rl = lane >> 2;
  const int cb = (lane & 3) * 8;
  f32x4 acc[4][4] = {};
  auto stage = [&](int k0, int buf) {   // exactly 4 gload_lds per thread
    GLOAD_LDS16(A  + (size_t)(m0 + rb + rl) * K + k0 + cb,      &As[buf][rb][0]);
    GLOAD_LDS16(A  + (size_t)(m0 + rb + 16 + rl) * K + k0 + cb, &As[buf][rb + 16][0]);
    GLOAD_LDS16(Bt + (size_t)(n0 + rb + rl) * K + k0 + cb,      &Bs[buf][rb][0]);
    GLOAD_LDS16(Bt + (size_t)(n0 + rb + 16 + rl) * K + k0 + cb, &Bs[buf][rb + 16][0]);
  };
  auto compute = [&](int buf) {
    half8 af[4], bf[4];
#pragma unroll
    for (int mt = 0; mt < 4; ++mt) af[mt] = *(half8*)&As[buf][wr * 64 + mt * 16 + l15][l4 * 8];
#pragma unroll
    for (int nt = 0; nt < 4; ++nt) bf[nt] = *(half8*)&Bs[buf][wc * 64 + nt * 16 + l15][l4 * 8];
    __builtin_amdgcn_s_setprio(1);
#pragma unroll
    for (int mt = 0; mt < 4; ++mt)
#pragma unroll
      for (int nt = 0; nt < 4; ++nt)
        acc[mt][nt] = __builtin_amdgcn_mfma_f32_16x16x32_f16(af[mt], bf[nt], acc[mt][nt], 0, 0, 0);
    __builtin_amdgcn_s_setprio(0);
  };
  stage(0, 0);
  stage(32, 1);
  for (int k0 = 0; k0 < K - 32; k0 += 32) {
    int buf = (k0 >> 5) & 1;
    WAITCNT4;
    __builtin_amdgcn_s_barrier();
    compute(buf);
    __builtin_amdgcn_s_barrier();
    if (k0 + 64 < K) stage(k0 + 64, buf);
  }
  WAITCNT0;
  __builtin_amdgcn_s_barrier();
  compute(((K - 32) >> 5) & 1);
#pragma unroll
  for (int mt = 0; mt < 4; ++mt)
#pragma unroll
    for (int nt = 0; nt < 4; ++nt)
#pragma unroll
      for (int r = 0; r < 4; ++r) {
        int row = m0 + wr * 64 + mt * 16 + l4 * 4 + r;
        int col = n0 + wc * 64 + nt * 16 + l15;
        Cc[(size_t)row * Nn + col] = (OutT)acc[mt][nt][r];
      }
}

// ---------------- flash attention: single-buffer gload_lds (r13-exact champion) ----------------
__global__ __launch_bounds__(256, 2) void attn_kernel(const _Float16* __restrict__ Qh,
                                                      const _Float16* __restrict__ KF,
                                                      const _Float16* __restrict__ VF,
                                                      _Float16* __restrict__ Oh) {
  __shared__ _Float16 KB[4096];
  __shared__ _Float16 VB[4096];
  const int tid = threadIdx.x, lane = tid & 63, w = tid >> 6;
  const int l15 = lane & 15, l4 = lane >> 4;
  int bid = blockIdx.x;
  int s = bid >> 3;
  int h = (bid & 7) * 2 + (s >> 5);
  int n0 = (s & 31) * 128;
  half8 qf[2][2];
#pragma unroll
  for (int qb = 0; qb < 2; ++qb)
#pragma unroll
    for (int kk = 0; kk < 2; ++kk)
      qf[qb][kk] = *(const half8*)(Qh + ((size_t)h * NT + n0 + w * 32 + qb * 16 + l15) * HD + kk * 32 + l4 * 8);
  f32x4 acc[2][4] = {};
  f32x4 acc5[2] = {};
  half8 of1 = {};
  if (l15 == 0) {
#pragma unroll
    for (int jq = 0; jq < 8; ++jq) of1[jq] = (_Float16)1.0f;
  }
  const _Float16* KFh = KF + (size_t)h * NT * HD + w * 512 + lane * 8;
  const _Float16* VFh = VF + (size_t)h * NT * HD + w * 512 + lane * 8;
  union U { half8 v; half2 p[4]; };
  for (int kb = 0; kb < 64; ++kb) {
    __syncthreads();
    {
      size_t g0 = (size_t)kb * 4096;
      GLOAD_LDS16(KFh + g0,        &KB[w * 512]);
      GLOAD_LDS16(KFh + g0 + 2048, &KB[2048 + w * 512]);
      GLOAD_LDS16(VFh + g0,        &VB[w * 512]);
      GLOAD_LDS16(VFh + g0 + 2048, &VB[2048 + w * 512]);
    }
    __syncthreads();
    f32x4 sv[2][4] = {};
    __builtin_amdgcn_s_setprio(1);
#pragma unroll
    for (int t = 0; t < 4; ++t)
#pragma unroll
      for (int kk = 0; kk < 2; ++kk) {
        half8 kf = *(half8*)&KB[(t * 2 + kk) * 512 + lane * 8];
        sv[0][t] = __builtin_amdgcn_mfma_f32_16x16x32_f16(kf, qf[0][kk], sv[0][t], 0, 0, 0);
        sv[1][t] = __builtin_amdgcn_mfma_f32_16x16x32_f16(kf, qf[1][kk], sv[1][t], 0, 0, 0);
      }
    __builtin_amdgcn_s_setprio(0);
    U u[2][2];
#pragma unroll
    for (int qb = 0; qb < 2; ++qb) {
      float e[4][4];
#pragma unroll
      for (int t = 0; t < 4; ++t)
#pragma unroll
        for (int r = 0; r < 4; ++r) e[t][r] = EXP2(sv[qb][t][r]);
      u[qb][0].p[0] = pk_f16(e[0][0], e[0][1]); u[qb][0].p[1] = pk_f16(e[0][2], e[0][3]);
      u[qb][0].p[2] = pk_f16(e[1][0], e[1][1]); u[qb][0].p[3] = pk_f16(e[1][2], e[1][3]);
      u[qb][1].p[0] = pk_f16(e[2][0], e[2][1]); u[qb][1].p[1] = pk_f16(e[2][2], e[2][3]);
      u[qb][1].p[2] = pk_f16(e[3][0], e[3][1]); u[qb][1].p[3] = pk_f16(e[3][2], e[3][3]);
    }
    __builtin_amdgcn_s_setprio(1);
#pragma unroll
    for (int t = 0; t < 4; ++t)
#pragma unroll
      for (int kk = 0; kk < 2; ++kk) {
        half8 vf = *(half8*)&VB[(t * 2 + kk) * 512 + lane * 8];
        acc[0][t] = __builtin_amdgcn_mfma_f32_16x16x32_f16(u[0][kk].v, vf, acc[0][t], 0, 0, 0);
        acc[1][t] = __builtin_amdgcn_mfma_f32_16x16x32_f16(u[1][kk].v, vf, acc[1][t], 0, 0, 0);
      }
    acc5[0] = __builtin_amdgcn_mfma_f32_16x16x32_f16(u[0][0].v, of1, acc5[0], 0, 0, 0);
    acc5[0] = __builtin_amdgcn_mfma_f32_16x16x32_f16(u[0][1].v, of1, acc5[0], 0, 0, 0);
    acc5[1] = __builtin_amdgcn_mfma_f32_16x16x32_f16(u[1][0].v, of1, acc5[1], 0, 0, 0);
    acc5[1] = __builtin_amdgcn_mfma_f32_16x16x32_f16(u[1][1].v, of1, acc5[1], 0, 0, 0);
    __builtin_amdgcn_s_setprio(0);
  }
#pragma unroll
  for (int qb = 0; qb < 2; ++qb) {
    float linv[4];
#pragma unroll
    for (int r = 0; r < 4; ++r) linv[r] = 1.0f / __shfl(acc5[qb][r], lane & 48);
#pragma unroll
    for (int t = 0; t < 4; ++t)
#pragma unroll
      for (int r = 0; r < 4; ++r) {
        int row = n0 + w * 32 + qb * 16 + l4 * 4 + r;
        Oh[(size_t)row * CH + h * HD + t * 16 + l15] = (_Float16)(acc[qb][t][r] * linv[r]);
      }
  }
}

extern "C" void kernel_launch(void* const* d_in, const int* in_sizes, int n_in,
                              void* d_out, int out_size, void* d_ws, size_t ws_size,
                              hipStream_t stream) {
  const float* x      = (const float*)d_in[0];
  const int*   coords = (const int*)d_in[1];
  const float* w_qkv  = (const float*)d_in[2];
  const float* w_out  = (const float*)d_in[3];
  const float* gq     = (const float*)d_in[4];
  const float* gk     = (const float*)d_in[5];
  float* out = (float*)d_out;

  char* ws = (char*)d_ws;
  size_t off = 0;
  auto alloc = [&](size_t bytes) { char* p = ws + off; off += bytes; return p; };
  _Float16* xh   = (_Float16*)alloc((size_t)NT * CH * 2);  // x f16
  _Float16* wqh  = (_Float16*)alloc((size_t)C3 * CH * 2);  // w_qkv f16
  _Float16* woh  = (_Float16*)alloc((size_t)CH * CH * 2);  // w_out f16
  float2*   csn  = (float2*)alloc((size_t)NT * 32 * 8);    // rope cos/sin table
  _Float16* Qh   = (_Float16*)alloc((size_t)NT * CH * 2);  // [H][N][64], pre-scaled
  _Float16* KFh  = (_Float16*)alloc((size_t)NT * CH * 2);  // frag-swizzled K
  _Float16* VFh  = (_Float16*)alloc((size_t)NT * CH * 2);  // frag-swizzled V
  _Float16* Oh   = (_Float16*)alloc((size_t)NT * CH * 2);  // attn out [N][C]
  if (off > ws_size) return;  // workspace too small: fail cleanly

  int na4 = NT * CH / 4, nb4 = C3 * CH / 4, nc4 = CH * CH / 4;
  int nprep = na4 + nb4 + nc4 + NT * 32;     // cvt ranges + rope range
  prep_kernel<<<(nprep + 255) / 256, 256, 0, stream>>>(x, na4, w_qkv, nb4, w_out, nc4,
                                                       coords, xh, wqh, woh, csn);
  gemm_qkv<<<(NT / 128) * (C3 / 256), 512, 0, stream>>>(xh, wqh, csn, gq, gk, Qh, KFh, VFh);
  attn_kernel<<<NH * (NT / 128), 256, 0, stream>>>(Qh, KFh, VFh, Oh);
  gemm_bt<float><<<(NT / 128) * (CH / 128), 256, 0, stream>>>(Oh, woh, out, NT, CH, CH, NT / 128);
}